// Round 2
// baseline (331.202 us; speedup 1.0000x reference)
//
#include <hip/hip_runtime.h>
#include <hip/hip_bf16.h>
#include <math.h>

// OLMoE sparse MoE block. fp32 storage, bf16 MFMA compute (32x32x16).
// T=1024, H=2048, I=1024, E=8, top-2, unweighted combine.
// Round 8 (resubmit; round-1 bench was an infra failure): halve N-tiles on
// both GEMMs to double active blocks (256 -> 512 => 2 blocks/CU, 8 waves/CU).
// Occupancy was grid-limited at 1 block/CU (10.7% measured, all pipes <16%
// => latency-bound).

#define NT 1024
#define HD 2048
#define ID 1024
#define NE 8
#define LDP 40   // LDS row pitch (bf16 elements)
#define MAXTILES 24

typedef __bf16 v8bf __attribute__((ext_vector_type(8)));
typedef __bf16 v2bf __attribute__((ext_vector_type(2)));
typedef float v16f __attribute__((ext_vector_type(16)));

__device__ __forceinline__ v8bf cvt8(float4 a, float4 b) {
    v8bf v;
    v[0] = (__bf16)a.x; v[1] = (__bf16)a.y; v[2] = (__bf16)a.z; v[3] = (__bf16)a.w;
    v[4] = (__bf16)b.x; v[5] = (__bf16)b.y; v[6] = (__bf16)b.z; v[7] = (__bf16)b.w;
    return v;
}

// ---------------- router: one wave per token ----------------
__global__ __launch_bounds__(256) void router_kernel(
    const float* __restrict__ x, const float* __restrict__ gw,
    float* __restrict__ logits_out, int* __restrict__ topids, int* __restrict__ counts)
{
    int wv = threadIdx.x >> 6, ln = threadIdx.x & 63;
    int t = blockIdx.x * 4 + wv;
    const float* xr = x + (size_t)t * HD + ln * 32;
    float4 xv[8];
#pragma unroll
    for (int i = 0; i < 8; i++) xv[i] = *(const float4*)(xr + i * 4);

    float lg[NE];
#pragma unroll
    for (int e = 0; e < NE; e++) {
        const float* wr = gw + (size_t)e * HD + ln * 32;
        float s = 0.f;
#pragma unroll
        for (int i = 0; i < 8; i++) {
            float4 w4 = *(const float4*)(wr + i * 4);
            s += xv[i].x * w4.x + xv[i].y * w4.y + xv[i].z * w4.z + xv[i].w * w4.w;
        }
#pragma unroll
        for (int off = 32; off > 0; off >>= 1) s += __shfl_down(s, off, 64);
        lg[e] = s;  // valid on lane 0
    }
    if (ln == 0) {
#pragma unroll
        for (int e = 0; e < NE; e++) logits_out[t * NE + e] = lg[e];
        int i1 = 0;
        for (int e = 1; e < NE; e++) if (lg[e] > lg[i1]) i1 = e;
        int i2 = -1;
        for (int e = 0; e < NE; e++) {
            if (e == i1) continue;
            if (i2 < 0 || lg[e] > lg[i2]) i2 = e;
        }
        topids[t * 2 + 0] = i1;
        topids[t * 2 + 1] = i2;
        atomicAdd(&counts[i1], 1);
        atomicAdd(&counts[i2], 1);
    }
}

// ---------------- scan + tile table ----------------
__global__ void scan_kernel(const int* __restrict__ counts, int* __restrict__ base,
                            int* __restrict__ cursor, int* __restrict__ tile_e,
                            int* __restrict__ tile_m)
{
    if (threadIdx.x == 0 && blockIdx.x == 0) {
        int s = 0, nt = 0;
        for (int e = 0; e < NE; e++) {
            base[e] = s; cursor[e] = s;
            for (int m0 = 0; m0 < counts[e]; m0 += 128) {
                tile_e[nt] = e; tile_m[nt] = m0; nt++;
            }
            s += counts[e];
        }
        for (int i = nt; i < MAXTILES; i++) tile_e[i] = -1;
    }
}

__global__ void assign_kernel(const int* __restrict__ topids, int* __restrict__ cursor,
                              int* __restrict__ rowtok, int* __restrict__ toppos)
{
    int t = blockIdx.x * blockDim.x + threadIdx.x;
    if (t < NT) {
#pragma unroll
        for (int s = 0; s < 2; s++) {
            int e = topids[t * 2 + s];
            int pos = atomicAdd(&cursor[e], 1);
            rowtok[pos] = t;
            toppos[t * 2 + s] = pos;
        }
    }
}

// ---------------- GEMM1: h = silu(X Wg) * (X Wu) ----------------
// block tile M128 x N32, tile-table driven, dbuf LDS + distance-2 reg prefetch.
// 4 waves, each computes one 32x32 output for g and u.
struct G1R { float4 a0, a1, a2, a3, b0, b1; };

__global__ __launch_bounds__(256) void gemm1_kernel(
    const float* __restrict__ x, const float* __restrict__ wg, const float* __restrict__ wu,
    const int* __restrict__ counts, const int* __restrict__ basev, const int* __restrict__ rowtok,
    const int* __restrict__ tile_e, const int* __restrict__ tile_m,
    __bf16* __restrict__ hbuf)
{
    int ti = blockIdx.y;
    int e = tile_e[ti];
    if (e < 0) return;
    int m0 = tile_m[ti];
    int cnt = counts[e];
    int n0 = blockIdx.x * 32;
    int base = basev[e];

    __shared__ __align__(16) __bf16 Ald[2][128][LDP];
    __shared__ __align__(16) __bf16 Bg[2][32][LDP];
    __shared__ __align__(16) __bf16 Bu[2][32][LDP];

    int tid = threadIdx.x;
    int w = tid >> 6, ln = tid & 63, ml = ln & 31, hh = ln >> 5;
    int wm = w * 32;

    int am = tid >> 1, aseg = tid & 1;
    const float* arow = nullptr;
    if (m0 + am < cnt) arow = x + (size_t)rowtok[base + m0 + am] * HD + aseg * 16;

    // B staging: 256 threads = {matsel: g/u} x {P: 16 k-pairs} x {s: 8 col groups}
    int s = tid & 7, P = (tid >> 3) & 15, matsel = tid >> 7;
    int bn = s * 4;
    int kp = P * 2;
    int bcol = 8 * (((P >> 2) ^ (s & 3)) ^ (s >> 2)) + 2 * (P & 3);
    const float* wbase = (matsel ? wu : wg) + (size_t)e * HD * ID + n0 + bn;
    __bf16* Bdst[2] = { matsel ? &Bu[0][0][0] : &Bg[0][0][0],
                        matsel ? &Bu[1][0][0] : &Bg[1][0][0] };

    v16f accg, accu;
#pragma unroll
    for (int r = 0; r < 16; r++) { accg[r] = 0.f; accu[r] = 0.f; }

    auto g1_load = [&](G1R& r, int K0) {
        if (arow) {
            r.a0 = *(const float4*)(arow + K0);
            r.a1 = *(const float4*)(arow + K0 + 4);
            r.a2 = *(const float4*)(arow + K0 + 8);
            r.a3 = *(const float4*)(arow + K0 + 12);
        } else { r.a0 = r.a1 = r.a2 = r.a3 = (float4){0,0,0,0}; }
        const float* pb = wbase + (size_t)(K0 + kp) * ID;
        r.b0 = *(const float4*)pb;
        r.b1 = *(const float4*)(pb + ID);
    };

    auto g1_store = [&](const G1R& r, int B) {
        *(v8bf*)&Ald[B][am][aseg * 16]     = cvt8(r.a0, r.a1);
        *(v8bf*)&Ald[B][am][aseg * 16 + 8] = cvt8(r.a2, r.a3);
        __bf16* bd = Bdst[B];
        float b0a[4] = {r.b0.x, r.b0.y, r.b0.z, r.b0.w};
        float b1a[4] = {r.b1.x, r.b1.y, r.b1.z, r.b1.w};
#pragma unroll
        for (int j = 0; j < 4; j++) {
            v2bf p; p[0] = (__bf16)b0a[j]; p[1] = (__bf16)b1a[j];
            *(v2bf*)&bd[(size_t)(bn + j) * LDP + bcol] = p;
        }
    };

    auto g1_mfma = [&](int B) {
#pragma unroll
        for (int kh = 0; kh < 2; kh++) {
            int kb = kh * 16 + hh * 8;
            int ho = kh * 2 + hh;
            int bc = 8 * ((ho ^ ((ml >> 2) & 3)) ^ ((ml >> 4) & 3));
            v8bf af = *(const v8bf*)&Ald[B][wm + ml][kb];
            v8bf bg = *(const v8bf*)&Bg[B][ml][bc];
            v8bf bu = *(const v8bf*)&Bu[B][ml][bc];
            accg = __builtin_amdgcn_mfma_f32_32x32x16_bf16(af, bg, accg, 0, 0, 0);
            accu = __builtin_amdgcn_mfma_f32_32x32x16_bf16(af, bu, accu, 0, 0, 0);
        }
    };

    const int NIT = HD / 32;  // 64, even
    G1R r0, r1;
    g1_load(r0, 0);
    g1_load(r1, 32);
    g1_store(r0, 0);
    __syncthreads();

    for (int it = 0; it < NIT; it += 2) {
        if (it + 2 < NIT) g1_load(r0, (it + 2) * 32);
        g1_mfma(0);
        if (it + 1 < NIT) g1_store(r1, 1);
        __syncthreads();
        if (it + 3 < NIT) g1_load(r1, (it + 3) * 32);
        g1_mfma(1);
        if (it + 2 < NIT) g1_store(r0, 0);
        __syncthreads();
    }

#pragma unroll
    for (int r = 0; r < 16; r++) {
        int row = wm + (r & 3) + 8 * (r >> 2) + 4 * hh;
        if (m0 + row < cnt) {
            float g = accg[r];
            float u = accu[r];
            float hv = g / (1.f + __expf(-g)) * u;
            hbuf[(size_t)(base + m0 + row) * ID + n0 + ml] = (__bf16)hv;
        }
    }
}

// ---------------- GEMM2: y = h Wd ----------------
// block tile M128 x N64, tile-table driven, dbuf LDS + distance-2 reg prefetch.
struct G2R { v8bf av0, av1; float4 d00, d10; };

__global__ __launch_bounds__(256) void gemm2_kernel(
    const __bf16* __restrict__ hbuf, const float* __restrict__ wd,
    const int* __restrict__ counts, const int* __restrict__ basev,
    const int* __restrict__ tile_e, const int* __restrict__ tile_m,
    __bf16* __restrict__ ybuf)
{
    int ti = blockIdx.y;
    int e = tile_e[ti];
    if (e < 0) return;
    int m0 = tile_m[ti];
    int cnt = counts[e];
    int n0 = blockIdx.x * 64;
    int base = basev[e];

    __shared__ __align__(16) __bf16 Ald[2][128][LDP];
    __shared__ __align__(16) __bf16 Bd[2][64][LDP];

    int tid = threadIdx.x;
    int w = tid >> 6, ln = tid & 63, ml = ln & 31, hh = ln >> 5;
    int wm = (w & 1) * 64, wn = (w >> 1) * 32;

    int am = tid >> 1, aseg = tid & 1;
    int grow = m0 + am;
    int arowi = base + (grow < cnt ? grow : (cnt - 1));
    const __bf16* ap0 = hbuf + (size_t)arowi * ID + aseg * 16;

    int s = tid & 15, P = tid >> 4;
    int bn = s * 4;
    int kp = P * 2;
    int bcol = 8 * (((P >> 2) ^ (s & 3)) ^ (s >> 2)) + 2 * (P & 3);
    const float* wde = wd + (size_t)e * ID * HD + n0 + bn;

    v16f acc[2];
#pragma unroll
    for (int mt = 0; mt < 2; mt++)
#pragma unroll
        for (int r = 0; r < 16; r++) acc[mt][r] = 0.f;

    auto g2_load = [&](G2R& r, int K0) {
        r.av0 = *(const v8bf*)(ap0 + K0);
        r.av1 = *(const v8bf*)(ap0 + K0 + 8);
        const float* p0 = wde + (size_t)(K0 + kp) * HD;
        r.d00 = *(const float4*)p0;
        r.d10 = *(const float4*)(p0 + HD);
    };

    auto g2_store = [&](const G2R& r, int B) {
        *(v8bf*)&Ald[B][am][aseg * 16]     = r.av0;
        *(v8bf*)&Ald[B][am][aseg * 16 + 8] = r.av1;
        float d0a[4] = {r.d00.x, r.d00.y, r.d00.z, r.d00.w};
        float d1a[4] = {r.d10.x, r.d10.y, r.d10.z, r.d10.w};
#pragma unroll
        for (int j = 0; j < 4; j++) {
            v2bf pd; pd[0] = (__bf16)d0a[j]; pd[1] = (__bf16)d1a[j];
            *(v2bf*)&Bd[B][bn + j][bcol] = pd;
        }
    };

    auto g2_mfma = [&](int B) {
#pragma unroll
        for (int kh = 0; kh < 2; kh++) {
            int kb = kh * 16 + hh * 8;
            int ho = kh * 2 + hh;
            int f0 = (ho ^ ((ml >> 2) & 3)) ^ (((wn + ml) >> 4) & 3);
            int bc0 = 8 * f0;
            v8bf af0 = *(const v8bf*)&Ald[B][wm + ml][kb];
            v8bf af1 = *(const v8bf*)&Ald[B][wm + 32 + ml][kb];
            v8bf bf0 = *(const v8bf*)&Bd[B][wn + ml][bc0];
            acc[0] = __builtin_amdgcn_mfma_f32_32x32x16_bf16(af0, bf0, acc[0], 0, 0, 0);
            acc[1] = __builtin_amdgcn_mfma_f32_32x32x16_bf16(af1, bf0, acc[1], 0, 0, 0);
        }
    };

    const int NIT = ID / 32;  // 32, even
    G2R r0, r1;
    g2_load(r0, 0);
    g2_load(r1, 32);
    g2_store(r0, 0);
    __syncthreads();

    for (int it = 0; it < NIT; it += 2) {
        if (it + 2 < NIT) g2_load(r0, (it + 2) * 32);
        g2_mfma(0);
        if (it + 1 < NIT) g2_store(r1, 1);
        __syncthreads();
        if (it + 3 < NIT) g2_load(r1, (it + 3) * 32);
        g2_mfma(1);
        if (it + 2 < NIT) g2_store(r0, 0);
        __syncthreads();
    }

#pragma unroll
    for (int mt = 0; mt < 2; mt++) {
#pragma unroll
        for (int r = 0; r < 16; r++) {
            int row = wm + mt * 32 + (r & 3) + 8 * (r >> 2) + 4 * hh;
            if (m0 + row < cnt) {
                ybuf[(size_t)(base + m0 + row) * HD + n0 + wn + ml] = (__bf16)acc[mt][r];
            }
        }
    }
}

// ---------------- combine ----------------
__global__ __launch_bounds__(256) void combine_kernel(
    const __bf16* __restrict__ ybuf, const int* __restrict__ toppos, float* __restrict__ out)
{
    int t = blockIdx.x;
    int tid = threadIdx.x;
    int p0 = toppos[t * 2 + 0];
    int p1 = toppos[t * 2 + 1];
    v8bf a = ((const v8bf*)(ybuf + (size_t)p0 * HD))[tid];
    v8bf b = ((const v8bf*)(ybuf + (size_t)p1 * HD))[tid];
    float4 o0, o1;
    o0.x = (float)a[0] + (float)b[0];
    o0.y = (float)a[1] + (float)b[1];
    o0.z = (float)a[2] + (float)b[2];
    o0.w = (float)a[3] + (float)b[3];
    o1.x = (float)a[4] + (float)b[4];
    o1.y = (float)a[5] + (float)b[5];
    o1.z = (float)a[6] + (float)b[6];
    o1.w = (float)a[7] + (float)b[7];
    float* orow = out + (size_t)t * HD + tid * 8;
    *(float4*)orow = o0;
    *(float4*)(orow + 4) = o1;
}

extern "C" void kernel_launch(void* const* d_in, const int* in_sizes, int n_in,
                              void* d_out, int out_size, void* d_ws, size_t ws_size,
                              hipStream_t stream)
{
    const float* x  = (const float*)d_in[0];
    const float* gw = (const float*)d_in[1];
    const float* wg = (const float*)d_in[2];
    const float* wu = (const float*)d_in[3];
    const float* wd = (const float*)d_in[4];
    float* out = (float*)d_out;
    float* logits = out + (size_t)NT * HD;

    char* ws = (char*)d_ws;
    int* counts = (int*)(ws + 0);
    int* base   = (int*)(ws + 64);
    int* cursor = (int*)(ws + 128);
    int* tile_e = (int*)(ws + 256);   // MAXTILES ints
    int* tile_m = (int*)(ws + 384);   // MAXTILES ints
    int* topids = (int*)(ws + 1024);
    int* toppos = (int*)(ws + 1024 + 8192);
    int* rowtok = (int*)(ws + 1024 + 16384);
    __bf16* hbuf = (__bf16*)(ws + 32768);                          // [2048,1024] bf16 = 4 MB
    __bf16* ybuf = (__bf16*)(ws + 32768 + (size_t)2048 * ID * 2);  // [2048,2048] bf16 = 8 MB

    hipMemsetAsync(ws, 0, 256, stream);
    router_kernel<<<NT / 4, 256, 0, stream>>>(x, gw, logits, topids, counts);
    scan_kernel<<<1, 64, 0, stream>>>(counts, base, cursor, tile_e, tile_m);
    assign_kernel<<<4, 256, 0, stream>>>(topids, cursor, rowtok, toppos);
    gemm1_kernel<<<dim3(ID / 32, MAXTILES), 256, 0, stream>>>(x, wg, wu, counts, base, rowtok, tile_e, tile_m, hbuf);
    gemm2_kernel<<<dim3(HD / 64, MAXTILES), 256, 0, stream>>>(hbuf, wd, counts, base, tile_e, tile_m, ybuf);
    combine_kernel<<<NT, 256, 0, stream>>>(ybuf, toppos, out);
}